// Round 5
// baseline (95.526 us; speedup 1.0000x reference)
//
#include <hip/hip_runtime.h>
#include <hip/hip_bf16.h>
#include <math.h>

// PNA layer, R5: pretrans on 32x32x16 MFMA (K=16=FE exact), reduced VALU stream.
//   u = h@W1 + b_pre  (bf16, precomputed)          W1 = W_pre rows 0:64
//   per 16-node group (256 edges):
//     v = h@W2 (2x2 16x16 MFMAs, wave-local -> v_lds)
//     per 32-edge x 32-col tile: acc = mfma32x32x16(ea, W3, Cinit = u[nbr]+v)
//     agg = [mean,max,min,std] over d: 8-reg in-lane trees + shfl_xor(32)
//     y1 = relu([h,agg]@Wfull + b_post1)           Wfull = scaler-folded [320][64]
//     out = y1@W_post2 + b_post2 + h
// MFMA layouts:
//   16x16x32 (m89-verified): A row=lane&15,k=(lane>>4)*8+j; B col=lane&15 same k;
//                            C col=lane&15,row=(lane>>4)*4+reg
//   32x32x16 (C/D m74/m101-verified): A row=lane&31,k=(lane>>5)*8+j;
//                            B col=lane&31,k=(lane>>5)*8+j;
//                            C col=lane&31,row=(reg&3)+8*(reg>>2)+4*(lane>>5)

#define N_NODES 65536
#define NGROUPS 4096
#define GRID_MAIN 1024

typedef float f32x4 __attribute__((ext_vector_type(4)));
typedef float f32x16 __attribute__((ext_vector_type(16)));
typedef short s16x8 __attribute__((ext_vector_type(8)));
typedef unsigned short us4 __attribute__((ext_vector_type(4)));

__device__ __forceinline__ unsigned short f2bf(float f) {     // manual RNE (cold paths)
    union { float f; unsigned int u; } v; v.f = f;
    unsigned int r = v.u + 0x7fffu + ((v.u >> 16) & 1u);
    return (unsigned short)(r >> 16);
}
__device__ __forceinline__ unsigned short f2bfh(float f) {    // compiler cvt (hot paths)
    __hip_bfloat16 b = __float2bfloat16(f);
    union { __hip_bfloat16 b; unsigned short u; } v; v.b = b; return v.u;
}
__device__ __forceinline__ float bf2f(unsigned short u) {
    union { unsigned int u; float f; } v; v.u = ((unsigned int)u) << 16; return v.f;
}

// ---------------- prep: transposed bf16 weights ----------------
__global__ __launch_bounds__(256) void k_w(const float* __restrict__ Wpre,
                                           const float* __restrict__ Wp1,
                                           const float* __restrict__ Wp2,
                                           unsigned short* __restrict__ wfullT,
                                           unsigned short* __restrict__ w2T,
                                           unsigned short* __restrict__ w3T,
                                           unsigned short* __restrict__ wp2T,
                                           float c1, float c2) {
    int c = blockIdx.x;            // output col 0..63
    int t = threadIdx.x;
    for (int k = t; k < 320; k += 256) {
        float v;
        if (k < 64) v = Wp1[k * 64 + c];
        else {
            int kk = k - 64;
            v = Wp1[(64 + kk) * 64 + c] + c1 * Wp1[(320 + kk) * 64 + c]
                                        + c2 * Wp1[(576 + kk) * 64 + c];
        }
        wfullT[c * 320 + k] = f2bf(v);
    }
    if (t < 64)              w2T[c * 64 + t]         = f2bf(Wpre[(64 + t) * 64 + c]);
    if (t < 16)              w3T[c * 16 + t]         = f2bf(Wpre[(128 + t) * 64 + c]);
    if (t >= 64 && t < 128)  wp2T[c * 64 + (t - 64)] = f2bf(Wp2[(t - 64) * 64 + c]);
}

// ---------------- u = h@W1 + b_pre (bf16) ----------------
__global__ __launch_bounds__(256) void k_u(const float* __restrict__ h,
                                           const float* __restrict__ Wpre,
                                           const float* __restrict__ b_pre,
                                           unsigned short* __restrict__ u) {
    __shared__ float W1[64 * 64];
    __shared__ float hl[16 * 64];
    int t = threadIdx.x;
    {
        const float4* ws = (const float4*)Wpre;
        float4* wd = (float4*)W1;
        #pragma unroll
        for (int q = 0; q < 4; ++q) wd[q * 256 + t] = ws[q * 256 + t];
    }
    int base = blockIdx.x * 1024;
    ((float4*)hl)[t] = ((const float4*)(h + base))[t];
    __syncthreads();
    int r = t >> 4, f4 = (t & 15) * 4;
    float a0 = 0.f, a1 = 0.f, a2 = 0.f, a3 = 0.f;
    #pragma unroll
    for (int k = 0; k < 64; k += 4) {
        float4 hv = *(const float4*)&hl[r * 64 + k];
        #define U_STEP(KK, HK)                                     \
        {   float hk = HK;                                         \
            float4 wu = *(const float4*)&W1[(k + KK) * 64 + f4];   \
            a0 = fmaf(hk, wu.x, a0); a1 = fmaf(hk, wu.y, a1);      \
            a2 = fmaf(hk, wu.z, a2); a3 = fmaf(hk, wu.w, a3); }
        U_STEP(0, hv.x) U_STEP(1, hv.y) U_STEP(2, hv.z) U_STEP(3, hv.w)
        #undef U_STEP
    }
    float4 bp = *(const float4*)&b_pre[f4];
    us4 o;
    o.x = f2bf(a0 + bp.x); o.y = f2bf(a1 + bp.y);
    o.z = f2bf(a2 + bp.z); o.w = f2bf(a3 + bp.w);
    *(us4*)&u[base + r * 64 + f4] = o;
}

// ---------------- fused main ----------------
__global__ __launch_bounds__(256, 3) void k_main(
    const float* __restrict__ h,
    const float* __restrict__ edge_attr,
    const int* __restrict__ nbr_idx,
    const float* __restrict__ b_post1,
    const float* __restrict__ b_post2,
    const unsigned short* __restrict__ u,       // [N][64] bf16
    const unsigned short* __restrict__ wfullT,  // [64][320] bf16
    const unsigned short* __restrict__ w2T,     // [64][64]
    const unsigned short* __restrict__ w3T,     // [64][16]
    const unsigned short* __restrict__ wp2T,    // [64][64]
    float* __restrict__ out) {
    __shared__ unsigned short A_lds[16 * 344];   // 11008 B  [node][h(64)|agg(256)|pad]
    __shared__ float h32[16 * 68];               // 4352 B
    __shared__ float v_lds[16 * 68];             // 4352 B   (wave-local RW, no barrier)
    __shared__ unsigned short y1_lds[16 * 72];   // 2304 B
    __shared__ int nbl[256];                     // 1024 B   -> 23040 B total

    int t = threadIdx.x;
    int lane = t & 63;
    int w = t >> 6;             // wave id
    int c = lane & 15;          // 16x16 frag col / A-row
    int g = lane >> 4;          // 16x16 k-group
    int l32 = lane & 31;        // 32x32 frag row/col
    int h2 = lane >> 5;         // 32x32 k-half
    int ct = w & 1;             // 32-col tile of this wave
    int colb = ct * 32 + l32;   // pretrans output col
    int col16 = w * 16 + c;     // post1/post2 output col

    // ---- register-resident weight B-fragments (loaded once per block) ----
    s16x8 wfull[10], w2f[2][2], wp2f[2], w3b;
    #pragma unroll
    for (int ks = 0; ks < 10; ++ks)
        wfull[ks] = *(const s16x8*)&wfullT[col16 * 320 + ks * 32 + g * 8];
    #pragma unroll
    for (int ks = 0; ks < 2; ++ks) {
        wp2f[ks] = *(const s16x8*)&wp2T[col16 * 64 + ks * 32 + g * 8];
        #pragma unroll
        for (int i2 = 0; i2 < 2; ++i2) {
            int cc = ct * 2 + i2;   // 16-col v tile
            w2f[i2][ks] = *(const s16x8*)&w2T[(cc * 16 + c) * 64 + ks * 32 + g * 8];
        }
    }
    w3b = *(const s16x8*)&w3T[colb * 16 + h2 * 8];   // 32x32 B-frag, K=16 exact
    float b1c = b_post1[col16];
    float b2c = b_post2[col16];

    for (int grp = blockIdx.x; grp < NGROUPS; grp += GRID_MAIN) {
        int node0 = grp * 16;

        // ---- stage h (fp32 + bf16 into A_lds) + neighbor indices ----
        {
            int r = t >> 4, q = t & 15;
            float4 hv = *((const float4*)(h + (size_t)node0 * 64) + t);
            *(float4*)&h32[r * 68 + q * 4] = hv;
            us4 o;
            o.x = f2bfh(hv.x); o.y = f2bfh(hv.y); o.z = f2bfh(hv.z); o.w = f2bfh(hv.w);
            *(us4*)&A_lds[r * 344 + q * 4] = o;
            nbl[t] = nbr_idx[node0 * 16 + t];
        }
        __syncthreads();

        // ---- v = h@W2 for this wave's 32 cols (2x 16-col tiles, wave-local) ----
        #pragma unroll
        for (int i2 = 0; i2 < 2; ++i2) {
            f32x4 vf = {0.f, 0.f, 0.f, 0.f};
            #pragma unroll
            for (int ks = 0; ks < 2; ++ks) {
                s16x8 a = *(const s16x8*)&A_lds[c * 344 + ks * 32 + g * 8];
                vf = __builtin_amdgcn_mfma_f32_16x16x32_bf16(a, w2f[i2][ks], vf, 0, 0, 0);
            }
            int cc = ct * 2 + i2;
            #pragma unroll
            for (int i = 0; i < 4; ++i)
                v_lds[(g * 4 + i) * 68 + cc * 16 + c] = vf[i];   // same-wave RW
        }

        // ---- pretrans: 4x 32x32x16 MFMA tiles (32 edges x 32 cols each) ----
        #pragma unroll
        for (int it = 0; it < 4; ++it) {
            int rt = (w >> 1) + 2 * it;          // row-tile 0..7 (32 edges)
            float v0 = v_lds[(2 * rt) * 68 + colb];
            float v1 = v_lds[(2 * rt + 1) * 68 + colb];

            // C-init: gathered u + v
            f32x16 acc;
            #pragma unroll
            for (int r = 0; r < 16; ++r) {
                int row = (r & 3) + 8 * (r >> 2) + 4 * h2;   // 0..31 within tile
                int j = nbl[rt * 32 + row];
                acc[r] = bf2f(u[(size_t)j * 64 + colb]) + ((r < 8) ? v0 : v1);
            }
            // A-frag: 8 consecutive fe of one edge row, straight from global fp32
            const float* p = edge_attr + ((size_t)node0 * 16 + rt * 32 + l32) * 16 + h2 * 8;
            float4 x0 = *(const float4*)p;
            float4 x1 = *(const float4*)(p + 4);
            s16x8 a;
            a[0] = (short)f2bfh(x0.x); a[1] = (short)f2bfh(x0.y);
            a[2] = (short)f2bfh(x0.z); a[3] = (short)f2bfh(x0.w);
            a[4] = (short)f2bfh(x1.x); a[5] = (short)f2bfh(x1.y);
            a[6] = (short)f2bfh(x1.z); a[7] = (short)f2bfh(x1.w);

            acc = __builtin_amdgcn_mfma_f32_32x32x16_bf16(a, w3b, acc, 0, 0, 0);

            // relu + per-node stats (regs 0..7 = node 2rt, regs 8..15 = node 2rt+1)
            float e0  = fmaxf(acc[0], 0.f),  e1  = fmaxf(acc[1], 0.f);
            float e2  = fmaxf(acc[2], 0.f),  e3  = fmaxf(acc[3], 0.f);
            float e4  = fmaxf(acc[4], 0.f),  e5  = fmaxf(acc[5], 0.f);
            float e6  = fmaxf(acc[6], 0.f),  e7  = fmaxf(acc[7], 0.f);
            float e8  = fmaxf(acc[8], 0.f),  e9  = fmaxf(acc[9], 0.f);
            float e10 = fmaxf(acc[10], 0.f), e11 = fmaxf(acc[11], 0.f);
            float e12 = fmaxf(acc[12], 0.f), e13 = fmaxf(acc[13], 0.f);
            float e14 = fmaxf(acc[14], 0.f), e15 = fmaxf(acc[15], 0.f);

            float s1a = ((e0 + e1) + (e2 + e3)) + ((e4 + e5) + (e6 + e7));
            float s2a = fmaf(e0, e0, fmaf(e1, e1, fmaf(e2, e2, fmaf(e3, e3,
                        fmaf(e4, e4, fmaf(e5, e5, fmaf(e6, e6, e7 * e7)))))));
            float mxa = fmaxf(fmaxf(fmaxf(e0, e1), fmaxf(e2, e3)),
                              fmaxf(fmaxf(e4, e5), fmaxf(e6, e7)));
            float mna = fminf(fminf(fminf(e0, e1), fminf(e2, e3)),
                              fminf(fminf(e4, e5), fminf(e6, e7)));
            float s1b = ((e8 + e9) + (e10 + e11)) + ((e12 + e13) + (e14 + e15));
            float s2b = fmaf(e8, e8, fmaf(e9, e9, fmaf(e10, e10, fmaf(e11, e11,
                        fmaf(e12, e12, fmaf(e13, e13, fmaf(e14, e14, e15 * e15)))))));
            float mxb = fmaxf(fmaxf(fmaxf(e8, e9), fmaxf(e10, e11)),
                              fmaxf(fmaxf(e12, e13), fmaxf(e14, e15)));
            float mnb = fminf(fminf(fminf(e8, e9), fminf(e10, e11)),
                              fminf(fminf(e12, e13), fminf(e14, e15)));

            s1a += __shfl_xor(s1a, 32); s2a += __shfl_xor(s2a, 32);
            mxa = fmaxf(mxa, __shfl_xor(mxa, 32)); mna = fminf(mna, __shfl_xor(mna, 32));
            s1b += __shfl_xor(s1b, 32); s2b += __shfl_xor(s2b, 32);
            mxb = fmaxf(mxb, __shfl_xor(mxb, 32)); mnb = fminf(mnb, __shfl_xor(mnb, 32));

            float ma = s1a * 0.0625f;
            float sda = sqrtf(fmaxf(fmaf(-ma, ma, s2a * 0.0625f), 0.f) + 1e-5f);
            float mb = s1b * 0.0625f;
            float sdb = sqrtf(fmaxf(fmaf(-mb, mb, s2b * 0.0625f), 0.f) + 1e-5f);

            if (h2 == 0) {   // lanes 0..31 write both nodes' 4 stats at col=colb
                unsigned short* pa = &A_lds[(2 * rt) * 344 + 64 + colb];
                pa[0]   = f2bfh(ma);
                pa[64]  = f2bfh(mxa);
                pa[128] = f2bfh(mna);
                pa[192] = f2bfh(sda);
                unsigned short* pb = &A_lds[(2 * rt + 1) * 344 + 64 + colb];
                pb[0]   = f2bfh(mb);
                pb[64]  = f2bfh(mxb);
                pb[128] = f2bfh(mnb);
                pb[192] = f2bfh(sdb);
            }
        }
        __syncthreads();

        // ---- post1: y1 = relu([h,agg]@Wfull + b1), K=320 ----
        {
            f32x4 y1 = {0.f, 0.f, 0.f, 0.f};
            #pragma unroll
            for (int ks = 0; ks < 10; ++ks) {
                s16x8 a = *(const s16x8*)&A_lds[c * 344 + ks * 32 + g * 8];
                y1 = __builtin_amdgcn_mfma_f32_16x16x32_bf16(a, wfull[ks], y1, 0, 0, 0);
            }
            #pragma unroll
            for (int i = 0; i < 4; ++i)
                y1_lds[(g * 4 + i) * 72 + col16] = f2bfh(fmaxf(y1[i] + b1c, 0.f));
        }
        __syncthreads();

        // ---- post2 + residual ----
        {
            f32x4 o = {0.f, 0.f, 0.f, 0.f};
            #pragma unroll
            for (int ks = 0; ks < 2; ++ks) {
                s16x8 a = *(const s16x8*)&y1_lds[c * 72 + ks * 32 + g * 8];
                o = __builtin_amdgcn_mfma_f32_16x16x32_bf16(a, wp2f[ks], o, 0, 0, 0);
            }
            #pragma unroll
            for (int i = 0; i < 4; ++i) {
                int r = g * 4 + i;
                out[(size_t)(node0 + r) * 64 + col16] = o[i] + b2c + h32[r * 68 + col16];
            }
        }
        __syncthreads();   // LDS reused next group
    }
}

extern "C" void kernel_launch(void* const* d_in, const int* in_sizes, int n_in,
                              void* d_out, int out_size, void* d_ws, size_t ws_size,
                              hipStream_t stream) {
    const float* h         = (const float*)d_in[0];
    const float* edge_attr = (const float*)d_in[1];
    const int*   nbr_idx   = (const int*)d_in[2];
    const float* W_pre     = (const float*)d_in[3];
    const float* b_pre     = (const float*)d_in[4];
    const float* W_post1   = (const float*)d_in[5];
    const float* b_post1   = (const float*)d_in[6];
    const float* W_post2   = (const float*)d_in[7];
    const float* b_post2   = (const float*)d_in[8];
    float* out = (float*)d_out;

    size_t need = (size_t)N_NODES * 64 * 2 + (64 * 320 + 64 * 64 + 64 * 16 + 64 * 64) * 2;
    if (ws_size < need) return;
    unsigned short* u      = (unsigned short*)d_ws;     // [N][64] bf16
    unsigned short* wfullT = u + (size_t)N_NODES * 64;  // [64][320]
    unsigned short* w2T    = wfullT + 64 * 320;         // [64][64]
    unsigned short* w3T    = w2T + 64 * 64;             // [64][16]
    unsigned short* wp2T   = w3T + 64 * 16;             // [64][64]

    double ld = log(16.0 + 1.0);                        // log(D+1)
    const double AVG = 2.302585092994046;
    float c1 = (float)(ld / AVG);
    float c2 = (float)(AVG / ld);

    k_w<<<64, 256, 0, stream>>>(W_pre, W_post1, W_post2, wfullT, w2T, w3T, wp2T, c1, c2);
    k_u<<<N_NODES / 16, 256, 0, stream>>>(h, W_pre, b_pre, u);
    k_main<<<GRID_MAIN, 256, 0, stream>>>(h, edge_attr, nbr_idx, b_post1, b_post2,
                                          u, wfullT, w2T, w3T, wp2T, out);
}

// Round 6
// 83.158 us; speedup vs baseline: 1.1487x; 1.1487x over previous
//
#include <hip/hip_runtime.h>
#include <hip/hip_bf16.h>
#include <math.h>

// PNA layer, R6: fused bf16-MFMA kernel, barrier-free pretrans, grid 4096.
//   u = h@W1 + b_pre (bf16, precomputed)   W1 = W_pre rows 0:64
//   v = h@W2         (bf16, precomputed)   W2 = W_pre rows 64:128
//   per 16-node block (256 edges):
//     per 32-edge x 32-col tile: acc = mfma32x32x16(ea_bf16, W3, Cinit = u[nbr]+v)
//     agg = [mean,max,min,std] over d: in-lane 8-reg trees + shfl_xor(32)
//     y1 = relu([h,agg]@Wfull + b_post1)   Wfull = scaler-folded [320][64]
//     out = y1@W_post2 + b_post2 + h
// MFMA layouts:
//   16x16x32 (m89-verified): A row=lane&15,k=(lane>>4)*8+j; B col=lane&15 same k;
//                            C col=lane&15,row=(lane>>4)*4+reg
//   32x32x16 (C/D m74/m101-verified): A row=lane&31,k=(lane>>5)*8+j;
//                            B col=lane&31,k=(lane>>5)*8+j;
//                            C col=lane&31,row=(reg&3)+8*(reg>>2)+4*(lane>>5)

#define N_NODES 65536
#define GRID_MAIN 4096

typedef float f32x4 __attribute__((ext_vector_type(4)));
typedef float f32x16 __attribute__((ext_vector_type(16)));
typedef short s16x8 __attribute__((ext_vector_type(8)));
typedef unsigned short us4 __attribute__((ext_vector_type(4)));

__device__ __forceinline__ unsigned short f2bf(float f) {     // manual RNE (cold paths)
    union { float f; unsigned int u; } v; v.f = f;
    unsigned int r = v.u + 0x7fffu + ((v.u >> 16) & 1u);
    return (unsigned short)(r >> 16);
}
__device__ __forceinline__ unsigned short f2bfh(float f) {    // compiler cvt (hot paths)
    __hip_bfloat16 b = __float2bfloat16(f);
    union { __hip_bfloat16 b; unsigned short u; } v; v.b = b; return v.u;
}
__device__ __forceinline__ float bf2f(unsigned short u) {
    union { unsigned int u; float f; } v; v.u = ((unsigned int)u) << 16; return v.f;
}

// ---------------- prep: transposed bf16 weights ----------------
__global__ __launch_bounds__(256) void k_w(const float* __restrict__ Wpre,
                                           const float* __restrict__ Wp1,
                                           const float* __restrict__ Wp2,
                                           unsigned short* __restrict__ wfullT,
                                           unsigned short* __restrict__ w3T,
                                           unsigned short* __restrict__ wp2T,
                                           float c1, float c2) {
    int c = blockIdx.x;            // output col 0..63
    int t = threadIdx.x;
    for (int k = t; k < 320; k += 256) {
        float v;
        if (k < 64) v = Wp1[k * 64 + c];
        else {
            int kk = k - 64;
            v = Wp1[(64 + kk) * 64 + c] + c1 * Wp1[(320 + kk) * 64 + c]
                                        + c2 * Wp1[(576 + kk) * 64 + c];
        }
        wfullT[c * 320 + k] = f2bf(v);
    }
    if (t < 16)              w3T[c * 16 + t]         = f2bf(Wpre[(128 + t) * 64 + c]);
    if (t >= 64 && t < 128)  wp2T[c * 64 + (t - 64)] = f2bf(Wp2[(t - 64) * 64 + c]);
}

// ---------------- u = h@W1 + b_pre ; v = h@W2 (both bf16) ----------------
__global__ __launch_bounds__(256) void k_uv(const float* __restrict__ h,
                                            const float* __restrict__ Wpre,
                                            const float* __restrict__ b_pre,
                                            unsigned short* __restrict__ u,
                                            unsigned short* __restrict__ v) {
    __shared__ float W12[128 * 64];   // 32 KB (W1 rows 0:64, W2 rows 64:128)
    __shared__ float hl[16 * 64];     // 4 KB
    int t = threadIdx.x;
    {
        const float4* ws = (const float4*)Wpre;
        float4* wd = (float4*)W12;
        #pragma unroll
        for (int q = 0; q < 8; ++q) wd[q * 256 + t] = ws[q * 256 + t];
    }
    int base = blockIdx.x * 1024;
    ((float4*)hl)[t] = ((const float4*)(h + base))[t];
    __syncthreads();
    int r = t >> 4, f4 = (t & 15) * 4;
    float au0 = 0.f, au1 = 0.f, au2 = 0.f, au3 = 0.f;
    float av0 = 0.f, av1 = 0.f, av2 = 0.f, av3 = 0.f;
    #pragma unroll
    for (int k = 0; k < 64; k += 4) {
        float4 hv = *(const float4*)&hl[r * 64 + k];
        #define UV_STEP(KK, HK)                                              \
        {   float hk = HK;                                                   \
            float4 wu = *(const float4*)&W12[(k + KK) * 64 + f4];            \
            float4 wv = *(const float4*)&W12[(64 + k + KK) * 64 + f4];       \
            au0 = fmaf(hk, wu.x, au0); au1 = fmaf(hk, wu.y, au1);            \
            au2 = fmaf(hk, wu.z, au2); au3 = fmaf(hk, wu.w, au3);            \
            av0 = fmaf(hk, wv.x, av0); av1 = fmaf(hk, wv.y, av1);            \
            av2 = fmaf(hk, wv.z, av2); av3 = fmaf(hk, wv.w, av3); }
        UV_STEP(0, hv.x) UV_STEP(1, hv.y) UV_STEP(2, hv.z) UV_STEP(3, hv.w)
        #undef UV_STEP
    }
    float4 bp = *(const float4*)&b_pre[f4];
    us4 uo, vo;
    uo.x = f2bf(au0 + bp.x); uo.y = f2bf(au1 + bp.y);
    uo.z = f2bf(au2 + bp.z); uo.w = f2bf(au3 + bp.w);
    vo.x = f2bf(av0); vo.y = f2bf(av1); vo.z = f2bf(av2); vo.w = f2bf(av3);
    *(us4*)&u[base + r * 64 + f4] = uo;
    *(us4*)&v[base + r * 64 + f4] = vo;
}

// ---------------- fused main: one 16-node group per block ----------------
__global__ __launch_bounds__(256, 4) void k_main(
    const float* __restrict__ h,
    const float* __restrict__ edge_attr,
    const int* __restrict__ nbr_idx,
    const float* __restrict__ b_post1,
    const float* __restrict__ b_post2,
    const unsigned short* __restrict__ u,       // [N][64] bf16
    const unsigned short* __restrict__ vbf,     // [N][64] bf16
    const unsigned short* __restrict__ wfullT,  // [64][320] bf16
    const unsigned short* __restrict__ w3T,     // [64][16]
    const unsigned short* __restrict__ wp2T,    // [64][64]
    float* __restrict__ out) {
    __shared__ unsigned short A_lds[16 * 344];   // 11008 B  [node][h(64)|agg(256)|pad]
    __shared__ unsigned short y1_lds[16 * 72];   // 2304 B   -> 13312 B total

    int t = threadIdx.x;
    int lane = t & 63;
    int w = t >> 6;             // wave id
    int c = lane & 15;          // 16x16 frag col / A-row
    int g = lane >> 4;          // 16x16 k-group
    int l32 = lane & 31;        // 32x32 frag row/col
    int h2 = lane >> 5;         // 32x32 k-half
    int ct = w & 1;             // 32-col tile of this wave
    int wr = w >> 1;            // row-tile parity
    int colb = ct * 32 + l32;   // pretrans output col
    int col16 = w * 16 + c;     // post1/post2 output col
    int node0 = blockIdx.x * 16;

    // ---- nbr indices for this wave's 4 row-tiles (independent, issues first) ----
    int jt0 = nbr_idx[node0 * 16 + (wr + 0) * 32 + l32];
    int jt1 = nbr_idx[node0 * 16 + (wr + 2) * 32 + l32];
    int jt2 = nbr_idx[node0 * 16 + (wr + 4) * 32 + l32];
    int jt3 = nbr_idx[node0 * 16 + (wr + 6) * 32 + l32];

    // ---- register-resident weight B-fragments ----
    s16x8 wfull[10], wp2f[2], w3b;
    #pragma unroll
    for (int ks = 0; ks < 10; ++ks)
        wfull[ks] = *(const s16x8*)&wfullT[col16 * 320 + ks * 32 + g * 8];
    #pragma unroll
    for (int ks = 0; ks < 2; ++ks)
        wp2f[ks] = *(const s16x8*)&wp2T[col16 * 64 + ks * 32 + g * 8];
    w3b = *(const s16x8*)&w3T[colb * 16 + h2 * 8];   // K=16 exact
    float b1c = b_post1[col16];
    float b2c = b_post2[col16];

    // ---- stage h as bf16 into A_lds rows (for post1) ----
    {
        int r = t >> 4, q = t & 15;
        float4 hv = *((const float4*)(h + (size_t)node0 * 64) + t);
        us4 o;
        o.x = f2bfh(hv.x); o.y = f2bfh(hv.y); o.z = f2bfh(hv.z); o.w = f2bfh(hv.w);
        *(us4*)&A_lds[r * 344 + q * 4] = o;
    }

    // ---- pretrans: 4x 32x32x16 MFMA tiles, NO barrier dependencies ----
    #pragma unroll
    for (int it = 0; it < 4; ++it) {
        int rt = wr + 2 * it;                    // row-tile 0..7 (32 edges)
        int jt = (it == 0) ? jt0 : (it == 1) ? jt1 : (it == 2) ? jt2 : jt3;
        float v0 = bf2f(vbf[(size_t)(node0 + 2 * rt) * 64 + colb]);
        float v1 = bf2f(vbf[(size_t)(node0 + 2 * rt + 1) * 64 + colb]);

        // C-init: gathered u + v  (j broadcast via shfl from the lane holding that row)
        f32x16 acc;
        #pragma unroll
        for (int r = 0; r < 16; ++r) {
            int row = (r & 3) + 8 * (r >> 2) + 4 * h2;   // 0..31 within tile
            int j = __shfl(jt, row);
            acc[r] = bf2f(u[(size_t)j * 64 + colb]) + ((r < 8) ? v0 : v1);
        }
        // A-frag: 8 consecutive fe of one edge row, straight from global fp32
        const float* p = edge_attr + ((size_t)node0 * 16 + rt * 32 + l32) * 16 + h2 * 8;
        float4 x0 = *(const float4*)p;
        float4 x1 = *(const float4*)(p + 4);
        s16x8 a;
        a[0] = (short)f2bfh(x0.x); a[1] = (short)f2bfh(x0.y);
        a[2] = (short)f2bfh(x0.z); a[3] = (short)f2bfh(x0.w);
        a[4] = (short)f2bfh(x1.x); a[5] = (short)f2bfh(x1.y);
        a[6] = (short)f2bfh(x1.z); a[7] = (short)f2bfh(x1.w);

        acc = __builtin_amdgcn_mfma_f32_32x32x16_bf16(a, w3b, acc, 0, 0, 0);

        // relu + per-node stats (regs 0..7 = node 2rt, 8..15 = node 2rt+1)
        float e0  = fmaxf(acc[0], 0.f),  e1  = fmaxf(acc[1], 0.f);
        float e2  = fmaxf(acc[2], 0.f),  e3  = fmaxf(acc[3], 0.f);
        float e4  = fmaxf(acc[4], 0.f),  e5  = fmaxf(acc[5], 0.f);
        float e6  = fmaxf(acc[6], 0.f),  e7  = fmaxf(acc[7], 0.f);
        float e8  = fmaxf(acc[8], 0.f),  e9  = fmaxf(acc[9], 0.f);
        float e10 = fmaxf(acc[10], 0.f), e11 = fmaxf(acc[11], 0.f);
        float e12 = fmaxf(acc[12], 0.f), e13 = fmaxf(acc[13], 0.f);
        float e14 = fmaxf(acc[14], 0.f), e15 = fmaxf(acc[15], 0.f);

        float s1a = ((e0 + e1) + (e2 + e3)) + ((e4 + e5) + (e6 + e7));
        float s2a = fmaf(e0, e0, fmaf(e1, e1, fmaf(e2, e2, fmaf(e3, e3,
                    fmaf(e4, e4, fmaf(e5, e5, fmaf(e6, e6, e7 * e7)))))));
        float mxa = fmaxf(fmaxf(fmaxf(e0, e1), fmaxf(e2, e3)),
                          fmaxf(fmaxf(e4, e5), fmaxf(e6, e7)));
        float mna = fminf(fminf(fminf(e0, e1), fminf(e2, e3)),
                          fminf(fminf(e4, e5), fminf(e6, e7)));
        float s1b = ((e8 + e9) + (e10 + e11)) + ((e12 + e13) + (e14 + e15));
        float s2b = fmaf(e8, e8, fmaf(e9, e9, fmaf(e10, e10, fmaf(e11, e11,
                    fmaf(e12, e12, fmaf(e13, e13, fmaf(e14, e14, e15 * e15)))))));
        float mxb = fmaxf(fmaxf(fmaxf(e8, e9), fmaxf(e10, e11)),
                          fmaxf(fmaxf(e12, e13), fmaxf(e14, e15)));
        float mnb = fminf(fminf(fminf(e8, e9), fminf(e10, e11)),
                          fminf(fminf(e12, e13), fminf(e14, e15)));

        s1a += __shfl_xor(s1a, 32); s2a += __shfl_xor(s2a, 32);
        mxa = fmaxf(mxa, __shfl_xor(mxa, 32)); mna = fminf(mna, __shfl_xor(mna, 32));
        s1b += __shfl_xor(s1b, 32); s2b += __shfl_xor(s2b, 32);
        mxb = fmaxf(mxb, __shfl_xor(mxb, 32)); mnb = fminf(mnb, __shfl_xor(mnb, 32));

        float ma = s1a * 0.0625f;
        float sda = sqrtf(fmaxf(fmaf(-ma, ma, s2a * 0.0625f), 0.f) + 1e-5f);
        float mb = s1b * 0.0625f;
        float sdb = sqrtf(fmaxf(fmaf(-mb, mb, s2b * 0.0625f), 0.f) + 1e-5f);

        if (h2 == 0) {   // lanes 0..31 write both nodes' 4 stats at col=colb
            unsigned short* pa = &A_lds[(2 * rt) * 344 + 64 + colb];
            pa[0]   = f2bfh(ma);
            pa[64]  = f2bfh(mxa);
            pa[128] = f2bfh(mna);
            pa[192] = f2bfh(sda);
            unsigned short* pb = &A_lds[(2 * rt + 1) * 344 + 64 + colb];
            pb[0]   = f2bfh(mb);
            pb[64]  = f2bfh(mxb);
            pb[128] = f2bfh(mnb);
            pb[192] = f2bfh(sdb);
        }
    }
    __syncthreads();

    // ---- post1: y1 = relu([h,agg]@Wfull + b1), K=320 ----
    {
        f32x4 y1 = {0.f, 0.f, 0.f, 0.f};
        #pragma unroll
        for (int ks = 0; ks < 10; ++ks) {
            s16x8 a = *(const s16x8*)&A_lds[c * 344 + ks * 32 + g * 8];
            y1 = __builtin_amdgcn_mfma_f32_16x16x32_bf16(a, wfull[ks], y1, 0, 0, 0);
        }
        #pragma unroll
        for (int i = 0; i < 4; ++i)
            y1_lds[(g * 4 + i) * 72 + col16] = f2bfh(fmaxf(y1[i] + b1c, 0.f));
    }
    __syncthreads();

    // ---- post2 + residual (h re-read from global; L1/L2-warm) ----
    {
        f32x4 o = {0.f, 0.f, 0.f, 0.f};
        #pragma unroll
        for (int ks = 0; ks < 2; ++ks) {
            s16x8 a = *(const s16x8*)&y1_lds[c * 72 + ks * 32 + g * 8];
            o = __builtin_amdgcn_mfma_f32_16x16x32_bf16(a, wp2f[ks], o, 0, 0, 0);
        }
        #pragma unroll
        for (int i = 0; i < 4; ++i) {
            int r = g * 4 + i;
            out[(size_t)(node0 + r) * 64 + col16] =
                o[i] + b2c + h[(size_t)(node0 + r) * 64 + col16];
        }
    }
}

extern "C" void kernel_launch(void* const* d_in, const int* in_sizes, int n_in,
                              void* d_out, int out_size, void* d_ws, size_t ws_size,
                              hipStream_t stream) {
    const float* h         = (const float*)d_in[0];
    const float* edge_attr = (const float*)d_in[1];
    const int*   nbr_idx   = (const int*)d_in[2];
    const float* W_pre     = (const float*)d_in[3];
    const float* b_pre     = (const float*)d_in[4];
    const float* W_post1   = (const float*)d_in[5];
    const float* b_post1   = (const float*)d_in[6];
    const float* W_post2   = (const float*)d_in[7];
    const float* b_post2   = (const float*)d_in[8];
    float* out = (float*)d_out;

    size_t need = (size_t)N_NODES * 64 * 2 * 2 + (64 * 320 + 64 * 16 + 64 * 64) * 2;
    if (ws_size < need) return;   // 16.05 MiB; harness provides >= 16.8 MiB (R2 precedent)
    unsigned short* u      = (unsigned short*)d_ws;       // [N][64] bf16
    unsigned short* vbf    = u + (size_t)N_NODES * 64;    // [N][64] bf16
    unsigned short* wfullT = vbf + (size_t)N_NODES * 64;  // [64][320]
    unsigned short* w3T    = wfullT + 64 * 320;           // [64][16]
    unsigned short* wp2T   = w3T + 64 * 16;               // [64][64]

    double ld = log(16.0 + 1.0);                          // log(D+1)
    const double AVG = 2.302585092994046;
    float c1 = (float)(ld / AVG);
    float c2 = (float)(AVG / ld);

    k_w<<<64, 256, 0, stream>>>(W_pre, W_post1, W_post2, wfullT, w3T, wp2T, c1, c2);
    k_uv<<<N_NODES / 16, 256, 0, stream>>>(h, W_pre, b_pre, u, vbf);
    k_main<<<GRID_MAIN, 256, 0, stream>>>(h, edge_attr, nbr_idx, b_post1, b_post2,
                                          u, vbf, wfullT, w3T, wp2T, out);
}

// Round 7
// 81.172 us; speedup vs baseline: 1.1768x; 1.0245x over previous
//
#include <hip/hip_runtime.h>
#include <hip/hip_bf16.h>
#include <math.h>

// PNA layer, R7: bf16 MFMA; LDS-broadcast nbr reads, saddr u-gather, deferred
// post-weights (register pressure cut), conflict-free LDS strides.
//   u = h@W1 + b_pre (bf16, precomputed)   W1 = W_pre rows 0:64
//   v = h@W2         (bf16, precomputed)   W2 = W_pre rows 64:128
//   per 16-node block (256 edges):
//     per 32-edge x 32-col tile: acc = mfma32x32x16(ea_bf16, W3, Cinit = u[nbr]+v)
//     agg = [mean,max,min,std] over d: in-lane 8-reg trees + shfl_xor(32)
//     y1 = relu([h,agg]@Wfull + b_post1)   Wfull = scaler-folded [320][64]
//     out = y1@W_post2 + b_post2 + h
// MFMA layouts:
//   16x16x32 (m89-verified): A row=lane&15,k=(lane>>4)*8+j; B col=lane&15 same k;
//                            C col=lane&15,row=(lane>>4)*4+reg
//   32x32x16 (C/D m74/m101-verified): A row=lane&31,k=(lane>>5)*8+j;
//                            B col=lane&31,k=(lane>>5)*8+j;
//                            C col=lane&31,row=(reg&3)+8*(reg>>2)+4*(lane>>5)

#define N_NODES 65536
#define GRID_MAIN 4096
#define ASTRIDE 348   // A_lds row stride (u16): 16 lanes c*174%32 all-distinct banks
#define YSTRIDE 76    // y1_lds row stride (u16): c*38%32 all-distinct banks

typedef float f32x4 __attribute__((ext_vector_type(4)));
typedef float f32x16 __attribute__((ext_vector_type(16)));
typedef short s16x8 __attribute__((ext_vector_type(8)));
typedef unsigned short us4 __attribute__((ext_vector_type(4)));

__device__ __forceinline__ unsigned short f2bf(float f) {     // manual RNE (cold paths)
    union { float f; unsigned int u; } v; v.f = f;
    unsigned int r = v.u + 0x7fffu + ((v.u >> 16) & 1u);
    return (unsigned short)(r >> 16);
}
__device__ __forceinline__ unsigned short f2bfh(float f) {    // compiler cvt (hot paths)
    __hip_bfloat16 b = __float2bfloat16(f);
    union { __hip_bfloat16 b; unsigned short u; } v; v.b = b; return v.u;
}
__device__ __forceinline__ float bf2f(unsigned short u) {
    union { unsigned int u; float f; } v; v.u = ((unsigned int)u) << 16; return v.f;
}

// ---------------- prep: transposed bf16 weights ----------------
__global__ __launch_bounds__(256) void k_w(const float* __restrict__ Wpre,
                                           const float* __restrict__ Wp1,
                                           const float* __restrict__ Wp2,
                                           unsigned short* __restrict__ wfullT,
                                           unsigned short* __restrict__ w3T,
                                           unsigned short* __restrict__ wp2T,
                                           float c1, float c2) {
    int c = blockIdx.x;            // output col 0..63
    int t = threadIdx.x;
    for (int k = t; k < 320; k += 256) {
        float v;
        if (k < 64) v = Wp1[k * 64 + c];
        else {
            int kk = k - 64;
            v = Wp1[(64 + kk) * 64 + c] + c1 * Wp1[(320 + kk) * 64 + c]
                                        + c2 * Wp1[(576 + kk) * 64 + c];
        }
        wfullT[c * 320 + k] = f2bf(v);
    }
    if (t < 16)              w3T[c * 16 + t]         = f2bf(Wpre[(128 + t) * 64 + c]);
    if (t >= 64 && t < 128)  wp2T[c * 64 + (t - 64)] = f2bf(Wp2[(t - 64) * 64 + c]);
}

// ---------------- u = h@W1 + b_pre ; v = h@W2 (both bf16) ----------------
__global__ __launch_bounds__(256) void k_uv(const float* __restrict__ h,
                                            const float* __restrict__ Wpre,
                                            const float* __restrict__ b_pre,
                                            unsigned short* __restrict__ u,
                                            unsigned short* __restrict__ v) {
    __shared__ float W12[128 * 64];   // 32 KB
    __shared__ float hl[16 * 64];     // 4 KB
    int t = threadIdx.x;
    {
        const float4* ws = (const float4*)Wpre;
        float4* wd = (float4*)W12;
        #pragma unroll
        for (int q = 0; q < 8; ++q) wd[q * 256 + t] = ws[q * 256 + t];
    }
    int base = blockIdx.x * 1024;
    ((float4*)hl)[t] = ((const float4*)(h + base))[t];
    __syncthreads();
    int r = t >> 4, f4 = (t & 15) * 4;
    float au0 = 0.f, au1 = 0.f, au2 = 0.f, au3 = 0.f;
    float av0 = 0.f, av1 = 0.f, av2 = 0.f, av3 = 0.f;
    #pragma unroll
    for (int k = 0; k < 64; k += 4) {
        float4 hv = *(const float4*)&hl[r * 64 + k];
        #define UV_STEP(KK, HK)                                              \
        {   float hk = HK;                                                   \
            float4 wu = *(const float4*)&W12[(k + KK) * 64 + f4];            \
            float4 wv = *(const float4*)&W12[(64 + k + KK) * 64 + f4];       \
            au0 = fmaf(hk, wu.x, au0); au1 = fmaf(hk, wu.y, au1);            \
            au2 = fmaf(hk, wu.z, au2); au3 = fmaf(hk, wu.w, au3);            \
            av0 = fmaf(hk, wv.x, av0); av1 = fmaf(hk, wv.y, av1);            \
            av2 = fmaf(hk, wv.z, av2); av3 = fmaf(hk, wv.w, av3); }
        UV_STEP(0, hv.x) UV_STEP(1, hv.y) UV_STEP(2, hv.z) UV_STEP(3, hv.w)
        #undef UV_STEP
    }
    float4 bp = *(const float4*)&b_pre[f4];
    us4 uo, vo;
    uo.x = f2bf(au0 + bp.x); uo.y = f2bf(au1 + bp.y);
    uo.z = f2bf(au2 + bp.z); uo.w = f2bf(au3 + bp.w);
    vo.x = f2bf(av0); vo.y = f2bf(av1); vo.z = f2bf(av2); vo.w = f2bf(av3);
    *(us4*)&u[base + r * 64 + f4] = uo;
    *(us4*)&v[base + r * 64 + f4] = vo;
}

// ---------------- fused main: one 16-node group per block ----------------
__global__ __launch_bounds__(256, 4) void k_main(
    const float* __restrict__ h,
    const float* __restrict__ edge_attr,
    const int* __restrict__ nbr_idx,
    const float* __restrict__ b_post1,
    const float* __restrict__ b_post2,
    const unsigned short* __restrict__ u,       // [N][64] bf16
    const unsigned short* __restrict__ vbf,     // [N][64] bf16
    const unsigned short* __restrict__ wfullT,  // [64][320] bf16 (L2-resident)
    const unsigned short* __restrict__ w3T,     // [64][16]
    const unsigned short* __restrict__ wp2T,    // [64][64]
    float* __restrict__ out) {
    __shared__ unsigned short A_lds[16 * ASTRIDE];   // 11136 B  [node][h(64)|agg(256)|pad]
    __shared__ unsigned short y1_lds[16 * YSTRIDE];  // 2432 B
    __shared__ int nbl[256];                         // 1024 B  -> 14592 B total

    int t = threadIdx.x;
    int lane = t & 63;
    int wu2 = __builtin_amdgcn_readfirstlane(t) >> 6;   // wave id, provably uniform
    int c = lane & 15;          // 16x16 frag col / A-row
    int g = lane >> 4;          // 16x16 k-group
    int l32 = lane & 31;        // 32x32 frag row/col
    int h2 = lane >> 5;         // 32x32 k-half
    int ct = wu2 & 1;           // 32-col tile of this wave (uniform)
    int wr = wu2 >> 1;          // row-tile base (uniform)
    int colb = ct * 32 + l32;   // pretrans output col
    int col16 = wu2 * 16 + c;   // post1/post2 output col
    int node0 = blockIdx.x * 16;

    // ---- w3 B-frag (hot, register-resident; wfull/wp2 deferred to use site) ----
    s16x8 w3b = *(const s16x8*)&w3T[colb * 16 + h2 * 8];
    float b1c = b_post1[col16];
    float b2c = b_post2[col16];

    // ---- stage h (bf16 into A_lds) + all 256 neighbor indices ----
    {
        int r = t >> 4, q = t & 15;
        float4 hv = *((const float4*)(h + (size_t)node0 * 64) + t);
        us4 o;
        o.x = f2bfh(hv.x); o.y = f2bfh(hv.y); o.z = f2bfh(hv.z); o.w = f2bfh(hv.w);
        *(us4*)&A_lds[r * ASTRIDE + q * 4] = o;
        nbl[t] = nbr_idx[node0 * 16 + t];
    }
    __syncthreads();

    // ---- pretrans: 4x 32x32x16 MFMA tiles ----
    #pragma unroll
    for (int it = 0; it < 4; ++it) {
        int rt = wr + 2 * it;                    // row-tile 0..7 (uniform)
        float v0 = bf2f(vbf[(unsigned)(((node0 + 2 * rt) << 6) | colb)]);
        float v1 = bf2f(vbf[(unsigned)(((node0 + 2 * rt + 1) << 6) | colb)]);

        // C-init: u[nbr] + v. j via broadcast ds_read (imm-offset, conflict-free);
        // u load is saddr + 32-bit voffset.
        f32x16 acc;
        #pragma unroll
        for (int r = 0; r < 16; ++r) {
            int row = (r & 3) + 8 * (r >> 2) + 4 * h2;   // C-frag row 0..31
            int j = nbl[rt * 32 + row];
            acc[r] = bf2f(u[(unsigned)((j << 6) | colb)]) + ((r < 8) ? v0 : v1);
        }
        // A-frag: 8 consecutive fe of this lane's edge row, straight from global fp32
        const float* p = edge_attr + ((size_t)node0 * 16 + rt * 32 + l32) * 16 + h2 * 8;
        float4 x0 = *(const float4*)p;
        float4 x1 = *(const float4*)(p + 4);
        s16x8 a;
        a[0] = (short)f2bfh(x0.x); a[1] = (short)f2bfh(x0.y);
        a[2] = (short)f2bfh(x0.z); a[3] = (short)f2bfh(x0.w);
        a[4] = (short)f2bfh(x1.x); a[5] = (short)f2bfh(x1.y);
        a[6] = (short)f2bfh(x1.z); a[7] = (short)f2bfh(x1.w);

        acc = __builtin_amdgcn_mfma_f32_32x32x16_bf16(a, w3b, acc, 0, 0, 0);

        // relu + per-node stats (regs 0..7 = node 2rt, 8..15 = node 2rt+1)
        float e0  = fmaxf(acc[0], 0.f),  e1  = fmaxf(acc[1], 0.f);
        float e2  = fmaxf(acc[2], 0.f),  e3  = fmaxf(acc[3], 0.f);
        float e4  = fmaxf(acc[4], 0.f),  e5  = fmaxf(acc[5], 0.f);
        float e6  = fmaxf(acc[6], 0.f),  e7  = fmaxf(acc[7], 0.f);
        float e8  = fmaxf(acc[8], 0.f),  e9  = fmaxf(acc[9], 0.f);
        float e10 = fmaxf(acc[10], 0.f), e11 = fmaxf(acc[11], 0.f);
        float e12 = fmaxf(acc[12], 0.f), e13 = fmaxf(acc[13], 0.f);
        float e14 = fmaxf(acc[14], 0.f), e15 = fmaxf(acc[15], 0.f);

        float s1a = ((e0 + e1) + (e2 + e3)) + ((e4 + e5) + (e6 + e7));
        float s2a = fmaf(e0, e0, fmaf(e1, e1, fmaf(e2, e2, e3 * e3)))
                  + fmaf(e4, e4, fmaf(e5, e5, fmaf(e6, e6, e7 * e7)));
        // linear chains fuse to v_max3/v_min3
        float mxa = fmaxf(fmaxf(fmaxf(fmaxf(fmaxf(fmaxf(fmaxf(e0, e1), e2), e3), e4), e5), e6), e7);
        float mna = fminf(fminf(fminf(fminf(fminf(fminf(fminf(e0, e1), e2), e3), e4), e5), e6), e7);
        float s1b = ((e8 + e9) + (e10 + e11)) + ((e12 + e13) + (e14 + e15));
        float s2b = fmaf(e8, e8, fmaf(e9, e9, fmaf(e10, e10, e11 * e11)))
                  + fmaf(e12, e12, fmaf(e13, e13, fmaf(e14, e14, e15 * e15)));
        float mxb = fmaxf(fmaxf(fmaxf(fmaxf(fmaxf(fmaxf(fmaxf(e8, e9), e10), e11), e12), e13), e14), e15);
        float mnb = fminf(fminf(fminf(fminf(fminf(fminf(fminf(e8, e9), e10), e11), e12), e13), e14), e15);

        s1a += __shfl_xor(s1a, 32); s2a += __shfl_xor(s2a, 32);
        mxa = fmaxf(mxa, __shfl_xor(mxa, 32)); mna = fminf(mna, __shfl_xor(mna, 32));
        s1b += __shfl_xor(s1b, 32); s2b += __shfl_xor(s2b, 32);
        mxb = fmaxf(mxb, __shfl_xor(mxb, 32)); mnb = fminf(mnb, __shfl_xor(mnb, 32));

        float ma = s1a * 0.0625f;
        float sda = sqrtf(fmaxf(fmaf(-ma, ma, s2a * 0.0625f), 0.f) + 1e-5f);
        float mb = s1b * 0.0625f;
        float sdb = sqrtf(fmaxf(fmaf(-mb, mb, s2b * 0.0625f), 0.f) + 1e-5f);

        if (h2 == 0) {   // lanes 0..31 write both nodes' 4 stats at col=colb
            unsigned short* pa = &A_lds[(2 * rt) * ASTRIDE + 64 + colb];
            pa[0]   = f2bfh(ma);
            pa[64]  = f2bfh(mxa);
            pa[128] = f2bfh(mna);
            pa[192] = f2bfh(sda);
            unsigned short* pb = &A_lds[(2 * rt + 1) * ASTRIDE + 64 + colb];
            pb[0]   = f2bfh(mb);
            pb[64]  = f2bfh(mxb);
            pb[128] = f2bfh(mnb);
            pb[192] = f2bfh(sdb);
        }
    }
    __syncthreads();

    // ---- post1: y1 = relu([h,agg]@Wfull + b1), K=320; weights from L2 table ----
    {
        f32x4 y1 = {0.f, 0.f, 0.f, 0.f};
        #pragma unroll
        for (int ks = 0; ks < 10; ++ks) {
            s16x8 wf = *(const s16x8*)&wfullT[col16 * 320 + ks * 32 + g * 8];
            s16x8 a  = *(const s16x8*)&A_lds[c * ASTRIDE + ks * 32 + g * 8];
            y1 = __builtin_amdgcn_mfma_f32_16x16x32_bf16(a, wf, y1, 0, 0, 0);
        }
        #pragma unroll
        for (int i = 0; i < 4; ++i)
            y1_lds[(g * 4 + i) * YSTRIDE + col16] = f2bfh(fmaxf(y1[i] + b1c, 0.f));
    }
    __syncthreads();

    // ---- post2 + residual (h re-read from global; L1/L2-warm) ----
    {
        f32x4 o = {0.f, 0.f, 0.f, 0.f};
        #pragma unroll
        for (int ks = 0; ks < 2; ++ks) {
            s16x8 wf = *(const s16x8*)&wp2T[col16 * 64 + ks * 32 + g * 8];
            s16x8 a  = *(const s16x8*)&y1_lds[c * YSTRIDE + ks * 32 + g * 8];
            o = __builtin_amdgcn_mfma_f32_16x16x32_bf16(a, wf, o, 0, 0, 0);
        }
        #pragma unroll
        for (int i = 0; i < 4; ++i) {
            int r = g * 4 + i;
            out[(size_t)(node0 + r) * 64 + col16] =
                o[i] + b2c + h[(size_t)(node0 + r) * 64 + col16];
        }
    }
}

extern "C" void kernel_launch(void* const* d_in, const int* in_sizes, int n_in,
                              void* d_out, int out_size, void* d_ws, size_t ws_size,
                              hipStream_t stream) {
    const float* h         = (const float*)d_in[0];
    const float* edge_attr = (const float*)d_in[1];
    const int*   nbr_idx   = (const int*)d_in[2];
    const float* W_pre     = (const float*)d_in[3];
    const float* b_pre     = (const float*)d_in[4];
    const float* W_post1   = (const float*)d_in[5];
    const float* b_post1   = (const float*)d_in[6];
    const float* W_post2   = (const float*)d_in[7];
    const float* b_post2   = (const float*)d_in[8];
    float* out = (float*)d_out;

    size_t need = (size_t)N_NODES * 64 * 2 * 2 + (64 * 320 + 64 * 16 + 64 * 64) * 2;
    if (ws_size < need) return;   // ~16.05 MiB
    unsigned short* u      = (unsigned short*)d_ws;       // [N][64] bf16
    unsigned short* vbf    = u + (size_t)N_NODES * 64;    // [N][64] bf16
    unsigned short* wfullT = vbf + (size_t)N_NODES * 64;  // [64][320]
    unsigned short* w3T    = wfullT + 64 * 320;           // [64][16]
    unsigned short* wp2T   = w3T + 64 * 16;               // [64][64]

    double ld = log(16.0 + 1.0);                          // log(D+1)
    const double AVG = 2.302585092994046;
    float c1 = (float)(ld / AVG);
    float c2 = (float)(AVG / ld);

    k_w<<<64, 256, 0, stream>>>(W_pre, W_post1, W_post2, wfullT, w3T, wp2T, c1, c2);
    k_uv<<<N_NODES / 16, 256, 0, stream>>>(h, W_pre, b_pre, u, vbf);
    k_main<<<GRID_MAIN, 256, 0, stream>>>(h, edge_attr, nbr_idx, b_post1, b_post2,
                                          u, vbf, wfullT, w3T, wp2T, out);
}

// Round 8
// 64.312 us; speedup vs baseline: 1.4854x; 1.2622x over previous
//
#include <hip/hip_runtime.h>
#include <hip/hip_bf16.h>
#include <math.h>

// PNA layer, R8: bf16 MFMA; zero-C MFMA with post-added gather (breaks the
// u-load -> MFMA critical path), ds_read_b128 broadcast neighbor offsets,
// MFMA-based prep kernel (uv + weight transpose fused into one launch).
//   u = h@W1 + b_pre (bf16, precomputed)   W1 = W_pre rows 0:64
//   v = h@W2         (bf16, precomputed)   W2 = W_pre rows 64:128
//   per 16-node block (256 edges):
//     per 32-edge x 32-col tile: acc = mfma32x32x16(ea_bf16, W3, 0)
//     e = relu(acc + u[nbr] + v);  agg = [mean,max,min,std] over d
//     y1 = relu([h,agg]@Wfull + b_post1)   Wfull = scaler-folded [320][64]
//     out = y1@W_post2 + b_post2 + h
// MFMA layouts:
//   16x16x32 (m89-verified): A row=lane&15,k=(lane>>4)*8+j; B col=lane&15 same k;
//                            C col=lane&15,row=(lane>>4)*4+reg
//   32x32x16 (C/D m74/m101-verified): A row=lane&31,k=(lane>>5)*8+j;
//                            B col=lane&31,k=(lane>>5)*8+j;
//                            C col=lane&31,row=(reg&3)+8*(reg>>2)+4*(lane>>5)

#define N_NODES 65536
#define NBLK (N_NODES / 16)       // 4096 uv blocks
#define GRID_PREP (NBLK + 64)     // + 64 weight-transpose blocks
#define ASTRIDE 348   // A_lds row stride (u16)
#define YSTRIDE 76    // y1_lds row stride (u16)

typedef float f32x4 __attribute__((ext_vector_type(4)));
typedef float f32x16 __attribute__((ext_vector_type(16)));
typedef short s16x8 __attribute__((ext_vector_type(8)));
typedef unsigned short us4 __attribute__((ext_vector_type(4)));
typedef int i32x4 __attribute__((ext_vector_type(4)));

__device__ __forceinline__ unsigned short f2bf(float f) {     // manual RNE
    union { float f; unsigned int u; } v; v.f = f;
    unsigned int r = v.u + 0x7fffu + ((v.u >> 16) & 1u);
    return (unsigned short)(r >> 16);
}
__device__ __forceinline__ unsigned short f2bfh(float f) {    // compiler cvt
    __hip_bfloat16 b = __float2bfloat16(f);
    union { __hip_bfloat16 b; unsigned short u; } v; v.b = b; return v.u;
}
__device__ __forceinline__ float bf2f(unsigned short u) {
    union { unsigned int u; float f; } v; v.u = ((unsigned int)u) << 16; return v.f;
}

// ---------------- prep: u/v via MFMA (blocks < NBLK) + weight transpose ----------------
__global__ __launch_bounds__(256) void k_prep(const float* __restrict__ h,
                                              const float* __restrict__ Wpre,
                                              const float* __restrict__ b_pre,
                                              const float* __restrict__ Wp1,
                                              const float* __restrict__ Wp2,
                                              unsigned short* __restrict__ u,
                                              unsigned short* __restrict__ vbf,
                                              unsigned short* __restrict__ wfullT,
                                              unsigned short* __restrict__ w3T,
                                              unsigned short* __restrict__ wp2T,
                                              float c1, float c2) {
    int t = threadIdx.x;
    if (blockIdx.x >= NBLK) {
        // ---- weight transpose blocks ----
        int c = blockIdx.x - NBLK;     // output col 0..63
        for (int k = t; k < 320; k += 256) {
            float v;
            if (k < 64) v = Wp1[k * 64 + c];
            else {
                int kk = k - 64;
                v = Wp1[(64 + kk) * 64 + c] + c1 * Wp1[(320 + kk) * 64 + c]
                                            + c2 * Wp1[(576 + kk) * 64 + c];
            }
            wfullT[c * 320 + k] = f2bf(v);
        }
        if (t < 16)              w3T[c * 16 + t]         = f2bf(Wpre[(128 + t) * 64 + c]);
        if (t >= 64 && t < 128)  wp2T[c * 64 + (t - 64)] = f2bf(Wp2[(t - 64) * 64 + c]);
        return;
    }

    // ---- uv blocks: [u|v] = h @ [W1|W2], 16 nodes, 4 waves x 32 cols ----
    __shared__ unsigned short hl[16 * 68];
    int lane = t & 63;
    int wv = __builtin_amdgcn_readfirstlane(t) >> 6;   // wave id (uniform)
    int c = lane & 15, g = lane >> 4;
    int node0 = blockIdx.x * 16;
    {
        int r = t >> 4, q = t & 15;
        float4 hv = *((const float4*)(h + (size_t)node0 * 64) + t);
        us4 o;
        o.x = f2bfh(hv.x); o.y = f2bfh(hv.y); o.z = f2bfh(hv.z); o.w = f2bfh(hv.w);
        *(us4*)&hl[r * 68 + q * 4] = o;
    }
    // B-frags on the fly from fp32 W_pre (L2-hot): wave wv covers concat cols
    // wv*32..wv*32+31 of [W1(64)|W2(64)]; waves 0,1 -> u, waves 2,3 -> v.
    s16x8 bf[2][2];
    int woff = (wv < 2) ? 0 : 64;                 // W_pre row offset
    #pragma unroll
    for (int i2 = 0; i2 < 2; ++i2) {
        int wcol = ((wv & 1) * 32) + i2 * 16 + c; // 0..63 within W1 or W2
        #pragma unroll
        for (int ks = 0; ks < 2; ++ks) {
            #pragma unroll
            for (int j = 0; j < 8; ++j)
                bf[i2][ks][j] = (short)f2bfh(Wpre[(woff + ks * 32 + g * 8 + j) * 64 + wcol]);
        }
    }
    __syncthreads();
    f32x4 acc0 = {0.f, 0.f, 0.f, 0.f}, acc1 = {0.f, 0.f, 0.f, 0.f};
    #pragma unroll
    for (int ks = 0; ks < 2; ++ks) {
        s16x8 a = *(const s16x8*)&hl[c * 68 + ks * 32 + g * 8];
        acc0 = __builtin_amdgcn_mfma_f32_16x16x32_bf16(a, bf[0][ks], acc0, 0, 0, 0);
        acc1 = __builtin_amdgcn_mfma_f32_16x16x32_bf16(a, bf[1][ks], acc1, 0, 0, 0);
    }
    unsigned short* dst = (wv < 2) ? u : vbf;
    #pragma unroll
    for (int i2 = 0; i2 < 2; ++i2) {
        int dcol = ((wv & 1) * 32) + i2 * 16 + c;
        float bp = (wv < 2) ? b_pre[dcol] : 0.f;
        const f32x4& av = i2 ? acc1 : acc0;
        #pragma unroll
        for (int i = 0; i < 4; ++i) {
            int row = g * 4 + i;
            dst[(size_t)(node0 + row) * 64 + dcol] = f2bfh(av[i] + bp);
        }
    }
}

// ---------------- fused main: one 16-node group per block ----------------
__global__ __launch_bounds__(256, 4) void k_main(
    const float* __restrict__ h,
    const float* __restrict__ edge_attr,
    const int* __restrict__ nbr_idx,
    const float* __restrict__ b_post1,
    const float* __restrict__ b_post2,
    const unsigned short* __restrict__ u,       // [N][64] bf16
    const unsigned short* __restrict__ vbf,     // [N][64] bf16
    const unsigned short* __restrict__ wfullT,  // [64][320] bf16 (L2-resident)
    const unsigned short* __restrict__ w3T,     // [64][16]
    const unsigned short* __restrict__ wp2T,    // [64][64]
    float* __restrict__ out) {
    __shared__ unsigned short A_lds[16 * ASTRIDE];   // 11136 B
    __shared__ unsigned short y1_lds[16 * YSTRIDE];  // 2432 B
    __shared__ int nbl[256];                         // 1024 B (byte offsets j<<7)

    int t = threadIdx.x;
    int lane = t & 63;
    int wu2 = __builtin_amdgcn_readfirstlane(t) >> 6;   // wave id (uniform)
    int c = lane & 15;          // 16x16 frag col / A-row
    int g = lane >> 4;          // 16x16 k-group
    int l32 = lane & 31;        // 32x32 frag row/col
    int h2 = lane >> 5;         // 32x32 k-half
    int ct = wu2 & 1;           // 32-col tile (uniform)
    int wr = wu2 >> 1;          // row-tile base (uniform)
    int colb = ct * 32 + l32;   // pretrans output col
    int cb2 = colb * 2;         // byte offset within a 128B u/v row
    int col16 = wu2 * 16 + c;   // post1/post2 output col
    int node0 = blockIdx.x * 16;

    s16x8 w3b = *(const s16x8*)&w3T[colb * 16 + h2 * 8];
    float b1c = b_post1[col16];
    float b2c = b_post2[col16];

    // ---- stage h (bf16) + neighbor byte-offsets ----
    {
        int r = t >> 4, q = t & 15;
        float4 hv = *((const float4*)(h + (size_t)node0 * 64) + t);
        us4 o;
        o.x = f2bfh(hv.x); o.y = f2bfh(hv.y); o.z = f2bfh(hv.z); o.w = f2bfh(hv.w);
        *(us4*)&A_lds[r * ASTRIDE + q * 4] = o;
        nbl[t] = nbr_idx[node0 * 16 + t] << 7;   // byte offset of u row
    }
    __syncthreads();

    const char* ub = (const char*)u;
    const char* vb = (const char*)vbf + ((unsigned)node0 << 7) + (unsigned)(wr * 256) + cb2;
    const char* eb = (const char*)edge_attr
                   + ((size_t)node0 * 16 + wr * 32 + l32) * 64 + h2 * 32;

    // ---- pretrans: 4x 32x32x16 MFMA tiles; u/v added AFTER the MFMA ----
    #pragma unroll
    for (int it = 0; it < 4; ++it) {
        int rt = wr + 2 * it;                    // row-tile 0..7 (uniform)

        // A-frag from global fp32 (independent of gather)
        float4 x0 = *(const float4*)(eb + it * 4096);
        float4 x1 = *(const float4*)(eb + it * 4096 + 16);
        s16x8 a;
        a[0] = (short)f2bfh(x0.x); a[1] = (short)f2bfh(x0.y);
        a[2] = (short)f2bfh(x0.z); a[3] = (short)f2bfh(x0.w);
        a[4] = (short)f2bfh(x1.x); a[5] = (short)f2bfh(x1.y);
        a[6] = (short)f2bfh(x1.z); a[7] = (short)f2bfh(x1.w);

        f32x16 acc = {};
        acc = __builtin_amdgcn_mfma_f32_32x32x16_bf16(a, w3b, acc, 0, 0, 0);

        // gathered u (16 scalar bf16, issued in parallel with the MFMA above)
        i32x4 jq0 = *(const i32x4*)&nbl[rt * 32 + 4 * h2 + 0];
        i32x4 jq1 = *(const i32x4*)&nbl[rt * 32 + 4 * h2 + 8];
        i32x4 jq2 = *(const i32x4*)&nbl[rt * 32 + 4 * h2 + 16];
        i32x4 jq3 = *(const i32x4*)&nbl[rt * 32 + 4 * h2 + 24];
        float uv[16];
        #pragma unroll
        for (int i = 0; i < 4; ++i) {
            uv[i]      = bf2f(*(const unsigned short*)(ub + (unsigned)(jq0[i] + cb2)));
            uv[4 + i]  = bf2f(*(const unsigned short*)(ub + (unsigned)(jq1[i] + cb2)));
            uv[8 + i]  = bf2f(*(const unsigned short*)(ub + (unsigned)(jq2[i] + cb2)));
            uv[12 + i] = bf2f(*(const unsigned short*)(ub + (unsigned)(jq3[i] + cb2)));
        }
        float v0 = bf2f(*(const unsigned short*)(vb + it * 512));
        float v1 = bf2f(*(const unsigned short*)(vb + it * 512 + 128));

        // e = relu(acc + u + v); per-node stats
        float e0  = fmaxf(acc[0]  + uv[0]  + v0, 0.f);
        float e1  = fmaxf(acc[1]  + uv[1]  + v0, 0.f);
        float e2  = fmaxf(acc[2]  + uv[2]  + v0, 0.f);
        float e3  = fmaxf(acc[3]  + uv[3]  + v0, 0.f);
        float e4  = fmaxf(acc[4]  + uv[4]  + v0, 0.f);
        float e5  = fmaxf(acc[5]  + uv[5]  + v0, 0.f);
        float e6  = fmaxf(acc[6]  + uv[6]  + v0, 0.f);
        float e7  = fmaxf(acc[7]  + uv[7]  + v0, 0.f);
        float e8  = fmaxf(acc[8]  + uv[8]  + v1, 0.f);
        float e9  = fmaxf(acc[9]  + uv[9]  + v1, 0.f);
        float e10 = fmaxf(acc[10] + uv[10] + v1, 0.f);
        float e11 = fmaxf(acc[11] + uv[11] + v1, 0.f);
        float e12 = fmaxf(acc[12] + uv[12] + v1, 0.f);
        float e13 = fmaxf(acc[13] + uv[13] + v1, 0.f);
        float e14 = fmaxf(acc[14] + uv[14] + v1, 0.f);
        float e15 = fmaxf(acc[15] + uv[15] + v1, 0.f);

        float s1a = ((e0 + e1) + (e2 + e3)) + ((e4 + e5) + (e6 + e7));
        float s2a = fmaf(e0, e0, fmaf(e1, e1, fmaf(e2, e2, e3 * e3)))
                  + fmaf(e4, e4, fmaf(e5, e5, fmaf(e6, e6, e7 * e7)));
        float mxa = fmaxf(fmaxf(fmaxf(fmaxf(fmaxf(fmaxf(fmaxf(e0, e1), e2), e3), e4), e5), e6), e7);
        float mna = fminf(fminf(fminf(fminf(fminf(fminf(fminf(e0, e1), e2), e3), e4), e5), e6), e7);
        float s1b = ((e8 + e9) + (e10 + e11)) + ((e12 + e13) + (e14 + e15));
        float s2b = fmaf(e8, e8, fmaf(e9, e9, fmaf(e10, e10, e11 * e11)))
                  + fmaf(e12, e12, fmaf(e13, e13, fmaf(e14, e14, e15 * e15)));
        float mxb = fmaxf(fmaxf(fmaxf(fmaxf(fmaxf(fmaxf(fmaxf(e8, e9), e10), e11), e12), e13), e14), e15);
        float mnb = fminf(fminf(fminf(fminf(fminf(fminf(fminf(e8, e9), e10), e11), e12), e13), e14), e15);

        s1a += __shfl_xor(s1a, 32); s2a += __shfl_xor(s2a, 32);
        mxa = fmaxf(mxa, __shfl_xor(mxa, 32)); mna = fminf(mna, __shfl_xor(mna, 32));
        s1b += __shfl_xor(s1b, 32); s2b += __shfl_xor(s2b, 32);
        mxb = fmaxf(mxb, __shfl_xor(mxb, 32)); mnb = fminf(mnb, __shfl_xor(mnb, 32));

        float ma = s1a * 0.0625f;
        float sda = sqrtf(fmaxf(fmaf(-ma, ma, s2a * 0.0625f), 0.f) + 1e-5f);
        float mb = s1b * 0.0625f;
        float sdb = sqrtf(fmaxf(fmaf(-mb, mb, s2b * 0.0625f), 0.f) + 1e-5f);

        if (h2 == 0) {
            unsigned short* pa = &A_lds[(2 * rt) * ASTRIDE + 64 + colb];
            pa[0]   = f2bfh(ma);
            pa[64]  = f2bfh(mxa);
            pa[128] = f2bfh(mna);
            pa[192] = f2bfh(sda);
            unsigned short* pb = &A_lds[(2 * rt + 1) * ASTRIDE + 64 + colb];
            pb[0]   = f2bfh(mb);
            pb[64]  = f2bfh(mxb);
            pb[128] = f2bfh(mnb);
            pb[192] = f2bfh(sdb);
        }
    }
    __syncthreads();

    // ---- post1: y1 = relu([h,agg]@Wfull + b1), K=320 ----
    {
        f32x4 y1 = {0.f, 0.f, 0.f, 0.f};
        #pragma unroll
        for (int ks = 0; ks < 10; ++ks) {
            s16x8 wf = *(const s16x8*)&wfullT[col16 * 320 + ks * 32 + g * 8];
            s16x8 a  = *(const s16x8*)&A_lds[c * ASTRIDE + ks * 32 + g * 8];
            y1 = __builtin_amdgcn_mfma_f32_16x16x32_bf16(a, wf, y1, 0, 0, 0);
        }
        #pragma unroll
        for (int i = 0; i < 4; ++i)
            y1_lds[(g * 4 + i) * YSTRIDE + col16] = f2bfh(fmaxf(y1[i] + b1c, 0.f));
    }
    __syncthreads();

    // ---- post2 + residual ----
    {
        f32x4 o = {0.f, 0.f, 0.f, 0.f};
        #pragma unroll
        for (int ks = 0; ks < 2; ++ks) {
            s16x8 wf = *(const s16x8*)&wp2T[col16 * 64 + ks * 32 + g * 8];
            s16x8 a  = *(const s16x8*)&y1_lds[c * YSTRIDE + ks * 32 + g * 8];
            o = __builtin_amdgcn_mfma_f32_16x16x32_bf16(a, wf, o, 0, 0, 0);
        }
        #pragma unroll
        for (int i = 0; i < 4; ++i) {
            int r = g * 4 + i;
            out[(size_t)(node0 + r) * 64 + col16] =
                o[i] + b2c + h[(size_t)(node0 + r) * 64 + col16];
        }
    }
}

extern "C" void kernel_launch(void* const* d_in, const int* in_sizes, int n_in,
                              void* d_out, int out_size, void* d_ws, size_t ws_size,
                              hipStream_t stream) {
    const float* h         = (const float*)d_in[0];
    const float* edge_attr = (const float*)d_in[1];
    const int*   nbr_idx   = (const int*)d_in[2];
    const float* W_pre     = (const float*)d_in[3];
    const float* b_pre     = (const float*)d_in[4];
    const float* W_post1   = (const float*)d_in[5];
    const float* b_post1   = (const float*)d_in[6];
    const float* W_post2   = (const float*)d_in[7];
    const float* b_post2   = (const float*)d_in[8];
    float* out = (float*)d_out;

    size_t need = (size_t)N_NODES * 64 * 2 * 2 + (64 * 320 + 64 * 16 + 64 * 64) * 2;
    if (ws_size < need) return;   // ~16.05 MiB
    unsigned short* u      = (unsigned short*)d_ws;       // [N][64] bf16
    unsigned short* vbf    = u + (size_t)N_NODES * 64;    // [N][64] bf16
    unsigned short* wfullT = vbf + (size_t)N_NODES * 64;  // [64][320]
    unsigned short* w3T    = wfullT + 64 * 320;           // [64][16]
    unsigned short* wp2T   = w3T + 64 * 16;               // [64][64]

    double ld = log(16.0 + 1.0);                          // log(D+1)
    const double AVG = 2.302585092994046;
    float c1 = (float)(ld / AVG);
    float c2 = (float)(AVG / ld);

    k_prep<<<GRID_PREP, 256, 0, stream>>>(h, W_pre, b_pre, W_post1, W_post2,
                                          u, vbf, wfullT, w3T, wp2T, c1, c2);
    k_main<<<NBLK, 256, 0, stream>>>(h, edge_attr, nbr_idx, b_post1, b_post2,
                                     u, vbf, wfullT, w3T, wp2T, out);
}